// Round 9
// baseline (265.199 us; speedup 1.0000x reference)
//
#include <hip/hip_runtime.h>
#include <math.h>

// Problem constants (reference: B,H,Q_TOK,D = 8,12,577,64)
constexpr int BB = 8, HH = 12, QT = 577, DD = 64;
constexpr int NTOK = BB * HH * QT;                        // 55392 tokens
constexpr long long MASK_ELEMS = (long long)NTOK * QT;    // 31,961,184
constexpr int NBH = BB * HH;                              // 96 bh-rows per q
constexpr int WAVES_PER_BLOCK = 8;                        // 512 threads
constexpr int CHUNKS = NBH / WAVES_PER_BLOCK;             // 12

using f4 = __attribute__((ext_vector_type(4))) float;
using f2 = __attribute__((ext_vector_type(2))) float;

// Verified mask math (R2-R7): hq = j0*g0+j1*g1+j2*g2; E = exp(hq) = 1/p
// (row max of p is exactly 1); mask = u/(u+(E-1)*(1-u)) [T==1].
// Edges exact: hq==0 -> E=1 -> m~=1 (ref 1.0); E=inf -> m=0 (ref 0).
template<bool T1>
__device__ __forceinline__ float mask_elem(float g0, float g1, float g2,
                                           float j0, float j1, float j2,
                                           float uv, float invT)
{
    const float hq = fmaxf(fmaf(j2, g2, fmaf(j1, g1, j0 * g0)), 0.0f);
    const float E  = __expf(hq);                 // hq==0 -> exactly 1
    const float a  = E - 1.0f;
    if (T1)
        return __fdividef(uv, fmaf(a, 1.0f - uv, uv));
    const float rr = __fdividef(a * (1.0f - uv), uv);
    return __fdividef(1.0f, 1.0f + __expf(__logf(rr) * invT));
}

// Mask row with geometry LOADED from the dists input (L1/L2-resident 2.66 MB;
// this block's 8 waves share one 4.6 KB row). dists is zero-padded at the CLS
// row/col by construction, so no q==0 / k==0 guards are needed at all.
// Replaces ~13 VALU ops/elem (incl. two quarter-rate int muls) with 8B loads
// on the lightly-loaded vmem pipe.  dq = dists + q*1154 (floats).
template<bool T1>
__device__ __forceinline__ void mask_row(int h, int NV, int lane,
                                         f4 uu0, f4 uu1, f4 uu2, int idx2,
                                         int scnt, int ks, float us,
                                         const float* __restrict__ dq,
                                         float j0, float j1, float j2,
                                         float invT,
                                         float* __restrict__ mp,
                                         float* __restrict__ out, unsigned base)
{
    // element k = h + 256*p + 4*lane + c  ->  float offset 2h + 512p + 8*lane + 2c
    const float* __restrict__ dp0 = dq + 2 * h + 8 * lane;
    {
        f4 m4;
#pragma unroll
        for (int c = 0; c < 4; ++c) {
            const f2 d = *(const f2*)(dp0 + 2 * c);          // 8B-aligned
            m4[c] = mask_elem<T1>(d.x * d.x, d.x * d.y, d.y * d.y,
                                  j0, j1, j2, uu0[c], invT);
        }
        __builtin_nontemporal_store(m4, (f4*)(mp + 4 * lane));
    }
    {
        const float* __restrict__ dp = dp0 + 512;
        f4 m4;
#pragma unroll
        for (int c = 0; c < 4; ++c) {
            const f2 d = *(const f2*)(dp + 2 * c);
            m4[c] = mask_elem<T1>(d.x * d.x, d.x * d.y, d.y * d.y,
                                  j0, j1, j2, uu1[c], invT);
        }
        __builtin_nontemporal_store(m4, (f4*)(mp + 4 * (64 + lane)));
    }
    if (idx2 < NV) {                             // pass 2: lanes 0..14/15
        const float* __restrict__ dp = dp0 + 1024;
        f4 m4;
#pragma unroll
        for (int c = 0; c < 4; ++c) {
            const f2 d = *(const f2*)(dp + 2 * c);
            m4[c] = mask_elem<T1>(d.x * d.x, d.x * d.y, d.y * d.y,
                                  j0, j1, j2, uu2[c], invT);
        }
        __builtin_nontemporal_store(m4, (f4*)(mp + 4 * idx2));
    }
    if (lane < scnt) {                           // head/tail leftovers (1 or 5)
        const f2 d = *(const f2*)(dq + 2 * ks);
        const float m = mask_elem<T1>(d.x * d.x, d.x * d.y, d.y * d.y,
                                      j0, j1, j2, us, invT);
        __builtin_nontemporal_store(m, out + base + ks);
    }
}

// ---------------------------------------------------------------------------
// FUSED v3 = verified R7 structure with memory-sourced geometry.
//   0: cooperative W1 -> LDS + query load.       [small vmem]
//   1: __syncthreads (drains only the tiny stage, NOT the u row).
//   2: issue u-row vec4 loads (nontemporal; single-use stream) -- then MLP
//      (64 x ds_read_b32 + readlane + fmaf) hides their HBM/L3 latency.
//   3: Sigma epilogue -> j0/j1/j2; Sigma store.
//   4: mask row: geometry via dists loads (L1-hot row), zero guards.
// LDS: 16 KB W1 only. No int-mul geometry, no G4 table.
// ---------------------------------------------------------------------------
__global__ __launch_bounds__(512, 6)
void fused_v3(const float* __restrict__ query,  // (NTOK, 64)
              const float* __restrict__ W1,     // (64, 64)
              const float* __restrict__ b1,     // (64)
              const float* __restrict__ W2,     // (64, 3)
              const float* __restrict__ b2,     // (3)
              const float* __restrict__ dists,  // (577, 577, 2) zero-padded CLS
              const float* __restrict__ u,      // (NTOK*577) flat
              const float* __restrict__ temp,   // (1)
              float* __restrict__ out)          // mask then Sigma
{
    __shared__ float W1s[DD * DD];               // 16 KB

    f4* __restrict__ SigOut = (f4*)(out + MASK_ELEMS);
    const int q     = blockIdx.x;                // 0..576
    const int chunk = blockIdx.y;                // 0..11
    const int tid   = threadIdx.x;
    const int wave  = tid >> 6, lane = tid & 63;

    const int token = (chunk * WAVES_PER_BLOCK + wave) * QT + q;
    const unsigned base = (unsigned)token * (unsigned)QT;
    const int h  = (int)((0u - base) & 3u);      // scalars to 16B align
    const int NV = (QT - h) >> 2;                // 143 or 144 vec4s
    const float* __restrict__ up = u   + base + h;
    float*       __restrict__ mp = out + base + h;
    const float* __restrict__ dq = dists + (unsigned)q * 1154u;

    // ---- phase 0: stage W1 -> LDS; load this wave's query element ----
    ((f4*)W1s)[tid]       = ((const f4*)W1)[tid];
    ((f4*)W1s)[tid + 512] = ((const f4*)W1)[tid + 512];
    const float qv   = query[(size_t)token * DD + lane];
    const float tval = temp[0];
    __syncthreads();                             // drains only the small stage

    // ---- phase 2a: issue u-row loads NOW (drain under the MLP) ----
    const f4 uu0 = __builtin_nontemporal_load((const f4*)(up + 4 * lane));
    const f4 uu1 = __builtin_nontemporal_load((const f4*)(up + 4 * (64 + lane)));
    const int idx2 = 128 + lane;
    f4 uu2 = {};
    if (idx2 < NV)
        uu2 = __builtin_nontemporal_load((const f4*)(up + 4 * idx2));
    const int scnt = QT - 4 * NV;                // 1 or 5 leftovers
    int ks = 0; float us = 0.0f;
    if (lane < scnt) {
        ks = (lane < h) ? lane : (h + 4 * NV + (lane - h));
        us = __builtin_nontemporal_load(u + base + ks);
    }

    // ---- phase 2b: MLP (exact verified chain; W1 via LDS, readlane bcast) --
    float acc = b1[lane];
#pragma unroll
    for (int i = 0; i < DD; ++i) {
        const float x = __int_as_float(
            __builtin_amdgcn_readlane(__float_as_int(qv), i));
        acc = fmaf(x, W1s[i * DD + lane], acc);  // ds_read_b32, 2-way free
    }
    const float hg = 0.5f * acc * (1.0f + erff(acc * 0.7071067811865476f));

    float p0 = hg * W2[lane * 3 + 0];
    float p1 = hg * W2[lane * 3 + 1];
    float p2 = hg * W2[lane * 3 + 2];
#pragma unroll
    for (int off = 32; off > 0; off >>= 1) {     // butterfly: all lanes get sums
        p0 += __shfl_xor(p0, off);
        p1 += __shfl_xor(p1, off);
        p2 += __shfl_xor(p2, off);
    }
    const float sy  = expf(p0 + b2[0]) + 1.0f;   // precise ocml for Sigma
    const float sx  = expf(p1 + b2[1]) + 1.0f;
    const float rho = tanhf(p2 + b2[2]) * 0.99f;
    const float cov = sy * sx * rho;
    const float Sx = sy * sy, Sw = sx * sx, Sy = cov;
    if (lane == 0) {
        f4 s; s.x = Sx; s.y = Sy; s.z = Sy; s.w = Sw;
        SigOut[token] = s;                       // Sigma output region
    }

    const float rdet = __fdividef(1.0f, fmaf(Sx, Sw, -Sy * Sy));
    const float j0 =  0.5f * Sw * rdet;          // 0.5*inv00
    const float j1 = -Sy * rdet;                 // inv01 (x2, x0.5 cancel)
    const float j2 =  0.5f * Sx * rdet;          // 0.5*inv11

    // scalar-uniform temperature branch: hot path has NO predicated cold ops
    const float invT = __int_as_float(__builtin_amdgcn_readfirstlane(
                           __float_as_int(__fdividef(1.0f, tval))));
    if (invT == 1.0f)
        mask_row<true >(h, NV, lane, uu0, uu1, uu2, idx2, scnt, ks, us,
                        dq, j0, j1, j2, invT, mp, out, base);
    else
        mask_row<false>(h, NV, lane, uu0, uu1, uu2, idx2, scnt, ks, us,
                        dq, j0, j1, j2, invT, mp, out, base);
}

extern "C" void kernel_launch(void* const* d_in, const int* in_sizes, int n_in,
                              void* d_out, int out_size, void* d_ws, size_t ws_size,
                              hipStream_t stream) {
    const float* query = (const float*)d_in[0];
    const float* W1    = (const float*)d_in[1];
    const float* b1    = (const float*)d_in[2];
    const float* W2    = (const float*)d_in[3];
    const float* b2    = (const float*)d_in[4];
    const float* dists = (const float*)d_in[5];
    const float* u     = (const float*)d_in[6];
    const float* temp  = (const float*)d_in[7];
    float* out = (float*)d_out;

    fused_v3<<<dim3(QT, CHUNKS), dim3(512), 0, stream>>>(
        query, W1, b1, W2, b2, dists, u, temp, out);
}